// Round 15
// baseline (758.430 us; speedup 1.0000x reference)
//
#include <hip/hip_runtime.h>
#include <math.h>

#define NB 16    // batch
#define SS 256   // spatial size (H = W = 256)
#define DV 32    // channels
#define MM 12    // w-dim (j) modes kept
#define MK 24    // h-dim (iy) modes kept (0..11 and 244..255)
#define LL 4     // layers
#define TWO_PI_N 0.024543692606170259679f   // 2*pi/256
#define TSTR 33  // LDS tile row stride (floats): 33 % 32 = 1 -> conflict-free b32

typedef float v2f __attribute__((ext_vector_type(2)));   // -> v_pk_fma_f32

// Workspace (floats):
//   h   : [NB][DV][SS][SS]            134 MB, in-place per layer
//   A   : [NB][MM][DV][SS(iy)][2]     12.6 MB  (row-DFT of h)
//   F   : [NB][ky:MM][m:MK][co:DV][2]  1.2 MB  (mixed spectral coeffs, pre-scaled)
//   g   : [NB][SS(iy)][MM][DV][2]     12.6 MB  (per-row spectral coeffs)
//   twT : [SS][MM][2]                  24 KB   (cos, -sin) of 2*pi*ky*j/256  (fwd DFT)
//   wT  : [LL][ci][co]                 16 KB   (transposed conv weights)
//   tw2 : [MM][SS][2]                  24 KB   (cos, +sin)  (inverse j-DFT, coalesced)

// --------------------------------------------- setup: tables + weight^T
__global__ __launch_bounds__(256) void k_prep(const float* __restrict__ ws_w,
        float* __restrict__ twT, float* __restrict__ wT, float* __restrict__ tw2)
{
    int j = threadIdx.x;
    #pragma unroll
    for (int k = 0; k < MM; ++k) {
        float ang = TWO_PI_N * (float)((k * j) & 255);
        float s, c; sincosf(ang, &s, &c);
        twT[j * (MM * 2) + 2 * k]     = c;
        twT[j * (MM * 2) + 2 * k + 1] = -s;
        tw2[(k * SS + j) * 2]     = c;
        tw2[(k * SS + j) * 2 + 1] = s;
    }
    for (int idx = threadIdx.x; idx < LL * DV * DV; idx += 256) {
        int l = idx >> 10, rem = idx & 1023, co = rem >> 5, ci = rem & 31;
        wT[(l * DV + ci) * DV + co] = ws_w[(l * DV + co) * DV + ci];
    }
}

// ---------------------------------------------------------------- lifting
// grid = NB*64; block = 4 rows, one wave per row, 4 px/thread (float4).
__global__ __launch_bounds__(256) void k_lift(const float* __restrict__ x,
        const float* __restrict__ p_w, const float* __restrict__ p_b,
        float* __restrict__ h)
{
    int tid = threadIdx.x;
    int lane = tid & 63;
    int w = __builtin_amdgcn_readfirstlane(tid >> 6);
    int b  = blockIdx.x >> 6;
    int iy = ((blockIdx.x & 63) << 2) + w;
    int j0 = lane << 2;

    float4 xv = *(const float4*)(x + ((size_t)(b * SS + iy)) * SS + j0);
    float gy = -1.f + 2.f * (float)iy * (1.f / 255.f);
    float4 gx;
    gx.x = -1.f + 2.f * (float)j0 * (1.f / 255.f);
    gx.y = gx.x + 2.f / 255.f; gx.z = gx.y + 2.f / 255.f; gx.w = gx.z + 2.f / 255.f;

    float* hb = h + ((size_t)b * DV * SS + iy) * SS + j0;
    #pragma unroll
    for (int c = 0; c < DV; ++c) {
        float w0 = p_w[3*c], w1 = p_w[3*c+1], w2 = p_w[3*c+2], bb = p_b[c];
        float4 v;
        v.x = w0 * xv.x + w1 * gy + w2 * gx.x + bb;
        v.y = w0 * xv.y + w1 * gy + w2 * gx.y + bb;
        v.z = w0 * xv.z + w1 * gy + w2 * gx.z + bb;
        v.w = w0 * xv.w + w1 * gy + w2 * gx.w + bb;
        *(float4*)(hb + (size_t)c * SS * SS) = v;
    }
}

// ------------------------------------------------- forward row (j) DFT, 12 modes
// block = (b, c, iy-half): grid 1024, 512 threads, (512,4) — VGPR headroom,
// LDS-limited occupancy. thread = (iy = tid&127, jq = tid>>7 wave-uniform).
// Accumulators as v2f (ar,ai) pairs -> v_pk_fma_f32 (half the VALU instrs).
__global__ __launch_bounds__(512, 4) void k_rowdft(const float* __restrict__ h,
        const float* __restrict__ twT, float* __restrict__ A)
{
    __shared__ float smem[6336];        // 24.75 KB: staging 128x33 / red 2x(24x128)
    int tid = threadIdx.x;
    int iy = tid & 127;
    int jq = __builtin_amdgcn_readfirstlane(tid >> 7);   // wave-uniform
    int bc = blockIdx.x >> 1;
    int iyh = blockIdx.x & 1;
    int b = bc >> 5, c = bc & 31;
    const float* hrow = h + (size_t)bc * SS * SS + (size_t)iyh * 128 * SS;

    v2f arai[MM];
    #pragma unroll
    for (int k = 0; k < MM; ++k) arai[k] = (v2f)(0.f);

    for (int t = 0; t < 8; ++t) {
        int jb = t * 32;
        __syncthreads();                 // smem free
        #pragma unroll
        for (int k = 0; k < 2; ++k) {
            int idx = tid + k * 512;     // 0..1023
            int row = idx >> 3, col4 = idx & 7;
            float4 v = *(const float4*)(hrow + (size_t)row * SS + jb + col4 * 4);
            float* d = &smem[row * TSTR + col4 * 4];
            d[0] = v.x; d[1] = v.y; d[2] = v.z; d[3] = v.w;
        }
        __syncthreads();
        const float* rp = &smem[iy * TSTR + jq * 8];
        #pragma unroll
        for (int i = 0; i < 8; ++i) {
            float v = rp[i];
            const v2f* twj = (const v2f*)(twT + (size_t)(jb + jq * 8 + i) * (MM * 2));
            #pragma unroll
            for (int k = 0; k < MM; ++k)
                arai[k] += twj[k] * v;   // packed (cos,-sin) fma
        }
    }

    // two-stage reduction over the 4 j-quarters
    __syncthreads();
    if (jq & 1) {                        // jq 1,3 write
        float* rd = &smem[(jq >> 1) * 3072];
        #pragma unroll
        for (int k = 0; k < MM; ++k) {
            rd[(2*k) * 128 + iy]     = arai[k].x;
            rd[(2*k + 1) * 128 + iy] = arai[k].y;
        }
    }
    __syncthreads();
    if (!(jq & 1)) {                     // jq 0,2 accumulate
        const float* rd = &smem[(jq >> 1) * 3072];
        #pragma unroll
        for (int k = 0; k < MM; ++k) {
            arai[k].x += rd[(2*k) * 128 + iy];
            arai[k].y += rd[(2*k + 1) * 128 + iy];
        }
    }
    __syncthreads();
    if (jq == 2) {
        #pragma unroll
        for (int k = 0; k < MM; ++k) {
            smem[(2*k) * 128 + iy]     = arai[k].x;
            smem[(2*k + 1) * 128 + iy] = arai[k].y;
        }
    }
    __syncthreads();
    if (jq == 0) {
        int iyg = iyh * 128 + iy;
        #pragma unroll
        for (int ky = 0; ky < MM; ++ky) {
            float2 val;
            val.x = arai[ky].x + smem[(2*ky) * 128 + iy];
            val.y = arai[ky].y + smem[(2*ky + 1) * 128 + iy];
            size_t o = ((((size_t)b * MM + ky) * DV + c) * SS + iyg) * 2;
            *(float2*)&A[o] = val;
        }
    }
}

// ---------- iy-DFT of A + channel mix -> F (pre-scaled)  (unchanged, proven)
__global__ __launch_bounds__(256, 4) void k_cm(const float* __restrict__ A,
        const float* __restrict__ w1r, const float* __restrict__ w1i,
        const float* __restrict__ w2r, const float* __restrict__ w2i,
        float* __restrict__ F, int l)
{
    __shared__ float FinS[DV][6][2];
    int blk = blockIdx.x;
    int mg = blk & 3;
    int bk = blk >> 2;                       // b*MM + ky
    int ky = bk % MM;
    int tid = threadIdx.x;
    int c = tid >> 3, ch = tid & 7;
    int iy0 = ch * 32;

    const float2* Ap = (const float2*)(A + ((size_t)bk * DV + c) * SS * 2);

    float fr[6], fi[6], pc[6], ps[6], sc[6], ssn[6];
    #pragma unroll
    for (int k = 0; k < 6; ++k) {
        int m = mg * 6 + k;
        int f = (m < MM) ? m : (232 + m);    // 244..255 for m >= 12
        float s, cc;
        sincosf(TWO_PI_N * (float)f, &s, &cc);
        sc[k] = cc; ssn[k] = s;
        sincosf(TWO_PI_N * (float)((f * iy0) & 255), &s, &cc);
        pc[k] = cc; ps[k] = s;
        fr[k] = fi[k] = 0.f;
    }
    #pragma unroll 4
    for (int i = 0; i < 32; ++i) {
        float2 a = Ap[iy0 + i];
        #pragma unroll
        for (int k = 0; k < 6; ++k) {
            fr[k] += a.x * pc[k] + a.y * ps[k];   // A * e^{-i th}
            fi[k] += a.y * pc[k] - a.x * ps[k];
            float np = pc[k] * sc[k] - ps[k] * ssn[k];
            float nq = pc[k] * ssn[k] + ps[k] * sc[k];
            pc[k] = np; ps[k] = nq;
        }
    }
    #pragma unroll
    for (int m = 1; m < 8; m <<= 1) {
        #pragma unroll
        for (int k = 0; k < 6; ++k) {
            fr[k] += __shfl_xor(fr[k], m, 64);
            fi[k] += __shfl_xor(fi[k], m, 64);
        }
    }
    #pragma unroll
    for (int k = 0; k < 6; ++k) {
        if (ch == k) { FinS[c][k][0] = fr[k]; FinS[c][k][1] = fi[k]; }
    }
    __syncthreads();

    if (ch < 6) {
        int o = c;
        int m = mg * 6 + ch;
        const float* Wr; const float* Wi; int xm;
        if (m < MM) { Wr = w1r; Wi = w1i; xm = m; }
        else        { Wr = w2r; Wi = w2i; xm = m - MM; }
        float scale = ((ky == 0) ? 1.0f : 2.0f) * (1.0f / 65536.0f);
        float orr = 0.f, oii = 0.f;
        #pragma unroll 4
        for (int i = 0; i < DV; ++i) {
            float gr = FinS[i][ch][0], gi = FinS[i][ch][1];
            size_t wi = ((size_t)(l * DV + i) * DV + o) * (MM * MM) + xm * MM + ky;
            float wr = Wr[wi], wim = Wi[wi];
            orr += gr * wr - gi * wim;
            oii += gr * wim + gi * wr;
        }
        size_t off = (((size_t)bk * MK + m) * DV + o) * 2;   // [ky][m][co]
        F[off] = orr * scale; F[off + 1] = oii * scale;
    }
}

// -------------------- inverse iy-DFT: F -> g[b][iy][ky][co][2]  (unchanged)
__global__ __launch_bounds__(384) void k_inv1(const float* __restrict__ F,
        float* __restrict__ g)
{
    __shared__ float itw[MK * 2];
    int tid = threadIdx.x;
    int b = blockIdx.x >> 8, iy = blockIdx.x & 255;
    if (tid < MK) {
        int f = (tid < MM) ? tid : (232 + tid);
        float ang = TWO_PI_N * (float)((f * iy) & 255);
        float s, c; sincosf(ang, &s, &c);
        itw[2 * tid] = c; itw[2 * tid + 1] = s;
    }
    __syncthreads();

    int ky = tid >> 5, co = tid & 31;
    const float* Fp = F + ((size_t)(b * MM + ky) * MK) * (DV * 2) + 2 * co;
    float gr = 0.f, gi = 0.f;
    #pragma unroll
    for (int m = 0; m < MK; ++m) {
        float2 fv = *(const float2*)(Fp + (size_t)m * (DV * 2));  // coalesced
        float ic = itw[2 * m], is = itw[2 * m + 1];
        gr += fv.x * ic - fv.y * is;
        gi += fv.x * is + fv.y * ic;
    }
    size_t o = (((size_t)(b * SS + iy)) * MM + ky) * (DV * 2) + 2 * co;
    g[o] = gr; g[o + 1] = gi;
}

// ----------------- pointwise: h = relu(conv1x1(h) + invDFT(F)), in place.
// grid = NB*128; block = 2 rows x 2 j-halves, 2 px/thread as v2f ->
// v_pk_fma_f32 (2 FLOP/lane/cyc — the fp32 peak path). (256,4), VGPR ~52.
// NOTE: never raise min-waves: acc[32] v2f = 64 live VGPRs (R13 spill disaster).
template<int FINAL>
__global__ __launch_bounds__(256, 4) void k_pt(float* __restrict__ h,
        const float* __restrict__ g, const float* __restrict__ wT,
        const float* __restrict__ ws_b, const float* __restrict__ tw2,
        const float* __restrict__ q_w, const float* __restrict__ q_b,
        float* __restrict__ out, int l)
{
    int tid = threadIdx.x;
    int lane = tid & 63;
    int w = __builtin_amdgcn_readfirstlane(tid >> 6);
    int b  = blockIdx.x >> 7;
    int iy = ((blockIdx.x & 127) << 1) + (w >> 1);
    int j0 = ((w & 1) << 7) + (lane << 1);

    float* hb = h + ((size_t)b * DV * SS + iy) * SS + j0;
    const float* wt  = wT + (size_t)l * DV * DV;     // [ci][co], uniform
    const float* wsb = ws_b + (size_t)l * DV;

    v2f acc[DV];
    #pragma unroll
    for (int co = 0; co < DV; ++co)
        acc[co] = (v2f)(wsb[co]);

    #pragma unroll 4
    for (int ci = 0; ci < DV; ++ci) {
        v2f hv = *(const v2f*)(hb + (size_t)ci * SS * SS);
        const float* wc = wt + ci * DV;              // 32 contiguous s_loads
        #pragma unroll
        for (int co = 0; co < DV; ++co)
            acc[co] += hv * wc[co];                  // v_pk_fma_f32
    }

    const float* gp = g + ((size_t)(b * SS + iy)) * (MM * DV * 2);  // uniform
    #pragma unroll 2
    for (int ky = 0; ky < MM; ++ky) {
        float4 t4 = *(const float4*)(tw2 + ((size_t)ky * SS + j0) * 2);
        v2f c2; c2.x = t4.x; c2.y = t4.z;            // cos(j0), cos(j0+1)
        v2f s2; s2.x = t4.y; s2.y = t4.w;            // sin(j0), sin(j0+1)
        const float* Gk = gp + ky * (DV * 2);        // 64 contiguous s_loads
        #pragma unroll
        for (int co = 0; co < DV; ++co) {
            float gr = Gk[2 * co], gi = Gk[2 * co + 1];
            acc[co] += c2 * gr - s2 * gi;            // 2x v_pk_fma_f32
        }
    }

    if (FINAL) {
        v2f o2 = (v2f)(q_b[0]);
        #pragma unroll
        for (int co = 0; co < DV; ++co)
            o2 += acc[co] * q_w[co];                 // packed
        *(v2f*)(out + ((size_t)(b * SS + iy)) * SS + j0) = o2;
    } else {
        #pragma unroll
        for (int co = 0; co < DV; ++co) {
            v2f v;
            v.x = fmaxf(acc[co].x, 0.f); v.y = fmaxf(acc[co].y, 0.f);
            *(v2f*)(hb + (size_t)co * SS * SS) = v;
        }
    }
}

extern "C" void kernel_launch(void* const* d_in, const int* in_sizes, int n_in,
                              void* d_out, int out_size, void* d_ws, size_t ws_size,
                              hipStream_t stream)
{
    const float* x    = (const float*)d_in[0];
    const float* p_w  = (const float*)d_in[1];
    const float* p_b  = (const float*)d_in[2];
    const float* ws_w = (const float*)d_in[3];
    const float* ws_b = (const float*)d_in[4];
    const float* w1r  = (const float*)d_in[5];
    const float* w1i  = (const float*)d_in[6];
    const float* w2r  = (const float*)d_in[7];
    const float* w2i  = (const float*)d_in[8];
    const float* q_w  = (const float*)d_in[9];
    const float* q_b  = (const float*)d_in[10];
    float* out = (float*)d_out;

    float* h   = (float*)d_ws;
    float* A   = h   + (size_t)NB * DV * SS * SS;
    float* F   = A   + (size_t)NB * MM * DV * SS * 2;
    float* g   = F   + (size_t)NB * MM * MK * DV * 2;
    float* twT = g   + (size_t)NB * SS * MM * DV * 2;
    float* wT  = twT + (size_t)SS * MM * 2;
    float* tw2 = wT  + (size_t)LL * DV * DV;

    dim3 blk(256);
    k_prep<<<1, blk, 0, stream>>>(ws_w, twT, wT, tw2);
    k_lift<<<NB * 64, blk, 0, stream>>>(x, p_w, p_b, h);
    for (int l = 0; l < LL; ++l) {
        k_rowdft<<<NB * DV * 2, dim3(512), 0, stream>>>(h, twT, A);
        k_cm<<<NB * MM * 4, blk, 0, stream>>>(A, w1r, w1i, w2r, w2i, F, l);
        k_inv1<<<NB * SS, dim3(384), 0, stream>>>(F, g);
        if (l < LL - 1)
            k_pt<0><<<NB * 128, blk, 0, stream>>>(h, g, wT, ws_b, tw2,
                                                  nullptr, nullptr, nullptr, l);
        else
            k_pt<1><<<NB * 128, blk, 0, stream>>>(h, g, wT, ws_b, tw2,
                                                  q_w, q_b, out, l);
    }
}

// Round 16
// 700.287 us; speedup vs baseline: 1.0830x; 1.0830x over previous
//
#include <hip/hip_runtime.h>
#include <math.h>

#define NB 16    // batch
#define SS 256   // spatial size (H = W = 256)
#define DV 32    // channels
#define MM 12    // w-dim (j) modes kept
#define MK 24    // h-dim (iy) modes kept (0..11 and 244..255)
#define LL 4     // layers
#define TWO_PI_N 0.024543692606170259679f   // 2*pi/256
#define TSTR 33  // LDS tile row stride (floats): 33 % 32 = 1 -> conflict-free b32

typedef float v2f __attribute__((ext_vector_type(2)));   // -> v_pk_fma_f32

// Workspace (floats):
//   h   : [NB][DV][SS][SS]            134 MB, in-place per layer
//   A   : [NB][MM][DV][SS(iy)][2]     12.6 MB  (row-DFT of h)
//   F   : [NB][ky:MM][m:MK][co:DV][2]  1.2 MB  (mixed spectral coeffs, pre-scaled)
//   g   : [NB][SS(iy)][MM][DV][2]     12.6 MB  (per-row spectral coeffs)
//   twT : [SS][MM][2]                  24 KB   (cos, -sin) of 2*pi*ky*j/256  (fwd DFT)
//   wT  : [LL][ci][co]                 16 KB   (transposed conv weights)
//   tw2 : [MM][SS][2]                  24 KB   (cos, +sin)  (inverse j-DFT, coalesced)

// --------------------------------------------- setup: tables + weight^T
__global__ __launch_bounds__(256) void k_prep(const float* __restrict__ ws_w,
        float* __restrict__ twT, float* __restrict__ wT, float* __restrict__ tw2)
{
    int j = threadIdx.x;
    #pragma unroll
    for (int k = 0; k < MM; ++k) {
        float ang = TWO_PI_N * (float)((k * j) & 255);
        float s, c; sincosf(ang, &s, &c);
        twT[j * (MM * 2) + 2 * k]     = c;
        twT[j * (MM * 2) + 2 * k + 1] = -s;
        tw2[(k * SS + j) * 2]     = c;
        tw2[(k * SS + j) * 2 + 1] = s;
    }
    for (int idx = threadIdx.x; idx < LL * DV * DV; idx += 256) {
        int l = idx >> 10, rem = idx & 1023, co = rem >> 5, ci = rem & 31;
        wT[(l * DV + ci) * DV + co] = ws_w[(l * DV + co) * DV + ci];
    }
}

// ---------------------------------------------------------------- lifting
// grid = NB*64; block = 4 rows, one wave per row, 4 px/thread (float4).
__global__ __launch_bounds__(256) void k_lift(const float* __restrict__ x,
        const float* __restrict__ p_w, const float* __restrict__ p_b,
        float* __restrict__ h)
{
    int tid = threadIdx.x;
    int lane = tid & 63;
    int w = __builtin_amdgcn_readfirstlane(tid >> 6);
    int b  = blockIdx.x >> 6;
    int iy = ((blockIdx.x & 63) << 2) + w;
    int j0 = lane << 2;

    float4 xv = *(const float4*)(x + ((size_t)(b * SS + iy)) * SS + j0);
    float gy = -1.f + 2.f * (float)iy * (1.f / 255.f);
    float4 gx;
    gx.x = -1.f + 2.f * (float)j0 * (1.f / 255.f);
    gx.y = gx.x + 2.f / 255.f; gx.z = gx.y + 2.f / 255.f; gx.w = gx.z + 2.f / 255.f;

    float* hb = h + ((size_t)b * DV * SS + iy) * SS + j0;
    #pragma unroll
    for (int c = 0; c < DV; ++c) {
        float w0 = p_w[3*c], w1 = p_w[3*c+1], w2 = p_w[3*c+2], bb = p_b[c];
        float4 v;
        v.x = w0 * xv.x + w1 * gy + w2 * gx.x + bb;
        v.y = w0 * xv.y + w1 * gy + w2 * gx.y + bb;
        v.z = w0 * xv.z + w1 * gy + w2 * gx.z + bb;
        v.w = w0 * xv.w + w1 * gy + w2 * gx.w + bb;
        *(float4*)(hb + (size_t)c * SS * SS) = v;
    }
}

// ------------------------------------------------- forward row (j) DFT, 12 modes
// block = (b, c, iy-half): grid 1024, 512 threads, (512,4). v2f accumulators
// (R15-proven win for this kernel: packed fma with scalar broadcast).
__global__ __launch_bounds__(512, 4) void k_rowdft(const float* __restrict__ h,
        const float* __restrict__ twT, float* __restrict__ A)
{
    __shared__ float smem[6336];        // 24.75 KB: staging 128x33 / red 2x(24x128)
    int tid = threadIdx.x;
    int iy = tid & 127;
    int jq = __builtin_amdgcn_readfirstlane(tid >> 7);   // wave-uniform
    int bc = blockIdx.x >> 1;
    int iyh = blockIdx.x & 1;
    int b = bc >> 5, c = bc & 31;
    const float* hrow = h + (size_t)bc * SS * SS + (size_t)iyh * 128 * SS;

    v2f arai[MM];
    #pragma unroll
    for (int k = 0; k < MM; ++k) arai[k] = (v2f)(0.f);

    for (int t = 0; t < 8; ++t) {
        int jb = t * 32;
        __syncthreads();                 // smem free
        #pragma unroll
        for (int k = 0; k < 2; ++k) {
            int idx = tid + k * 512;     // 0..1023
            int row = idx >> 3, col4 = idx & 7;
            float4 v = *(const float4*)(hrow + (size_t)row * SS + jb + col4 * 4);
            float* d = &smem[row * TSTR + col4 * 4];
            d[0] = v.x; d[1] = v.y; d[2] = v.z; d[3] = v.w;
        }
        __syncthreads();
        const float* rp = &smem[iy * TSTR + jq * 8];
        #pragma unroll
        for (int i = 0; i < 8; ++i) {
            float v = rp[i];
            const v2f* twj = (const v2f*)(twT + (size_t)(jb + jq * 8 + i) * (MM * 2));
            #pragma unroll
            for (int k = 0; k < MM; ++k)
                arai[k] += twj[k] * v;   // packed (cos,-sin) fma
        }
    }

    // two-stage reduction over the 4 j-quarters
    __syncthreads();
    if (jq & 1) {                        // jq 1,3 write
        float* rd = &smem[(jq >> 1) * 3072];
        #pragma unroll
        for (int k = 0; k < MM; ++k) {
            rd[(2*k) * 128 + iy]     = arai[k].x;
            rd[(2*k + 1) * 128 + iy] = arai[k].y;
        }
    }
    __syncthreads();
    if (!(jq & 1)) {                     // jq 0,2 accumulate
        const float* rd = &smem[(jq >> 1) * 3072];
        #pragma unroll
        for (int k = 0; k < MM; ++k) {
            arai[k].x += rd[(2*k) * 128 + iy];
            arai[k].y += rd[(2*k + 1) * 128 + iy];
        }
    }
    __syncthreads();
    if (jq == 2) {
        #pragma unroll
        for (int k = 0; k < MM; ++k) {
            smem[(2*k) * 128 + iy]     = arai[k].x;
            smem[(2*k + 1) * 128 + iy] = arai[k].y;
        }
    }
    __syncthreads();
    if (jq == 0) {
        int iyg = iyh * 128 + iy;
        #pragma unroll
        for (int ky = 0; ky < MM; ++ky) {
            float2 val;
            val.x = arai[ky].x + smem[(2*ky) * 128 + iy];
            val.y = arai[ky].y + smem[(2*ky + 1) * 128 + iy];
            size_t o = ((((size_t)b * MM + ky) * DV + c) * SS + iyg) * 2;
            *(float2*)&A[o] = val;
        }
    }
}

// ---------- iy-DFT of A + channel mix -> F (pre-scaled)  (unchanged, proven)
__global__ __launch_bounds__(256, 4) void k_cm(const float* __restrict__ A,
        const float* __restrict__ w1r, const float* __restrict__ w1i,
        const float* __restrict__ w2r, const float* __restrict__ w2i,
        float* __restrict__ F, int l)
{
    __shared__ float FinS[DV][6][2];
    int blk = blockIdx.x;
    int mg = blk & 3;
    int bk = blk >> 2;                       // b*MM + ky
    int ky = bk % MM;
    int tid = threadIdx.x;
    int c = tid >> 3, ch = tid & 7;
    int iy0 = ch * 32;

    const float2* Ap = (const float2*)(A + ((size_t)bk * DV + c) * SS * 2);

    float fr[6], fi[6], pc[6], ps[6], sc[6], ssn[6];
    #pragma unroll
    for (int k = 0; k < 6; ++k) {
        int m = mg * 6 + k;
        int f = (m < MM) ? m : (232 + m);    // 244..255 for m >= 12
        float s, cc;
        sincosf(TWO_PI_N * (float)f, &s, &cc);
        sc[k] = cc; ssn[k] = s;
        sincosf(TWO_PI_N * (float)((f * iy0) & 255), &s, &cc);
        pc[k] = cc; ps[k] = s;
        fr[k] = fi[k] = 0.f;
    }
    #pragma unroll 4
    for (int i = 0; i < 32; ++i) {
        float2 a = Ap[iy0 + i];
        #pragma unroll
        for (int k = 0; k < 6; ++k) {
            fr[k] += a.x * pc[k] + a.y * ps[k];   // A * e^{-i th}
            fi[k] += a.y * pc[k] - a.x * ps[k];
            float np = pc[k] * sc[k] - ps[k] * ssn[k];
            float nq = pc[k] * ssn[k] + ps[k] * sc[k];
            pc[k] = np; ps[k] = nq;
        }
    }
    #pragma unroll
    for (int m = 1; m < 8; m <<= 1) {
        #pragma unroll
        for (int k = 0; k < 6; ++k) {
            fr[k] += __shfl_xor(fr[k], m, 64);
            fi[k] += __shfl_xor(fi[k], m, 64);
        }
    }
    #pragma unroll
    for (int k = 0; k < 6; ++k) {
        if (ch == k) { FinS[c][k][0] = fr[k]; FinS[c][k][1] = fi[k]; }
    }
    __syncthreads();

    if (ch < 6) {
        int o = c;
        int m = mg * 6 + ch;
        const float* Wr; const float* Wi; int xm;
        if (m < MM) { Wr = w1r; Wi = w1i; xm = m; }
        else        { Wr = w2r; Wi = w2i; xm = m - MM; }
        float scale = ((ky == 0) ? 1.0f : 2.0f) * (1.0f / 65536.0f);
        float orr = 0.f, oii = 0.f;
        #pragma unroll 4
        for (int i = 0; i < DV; ++i) {
            float gr = FinS[i][ch][0], gi = FinS[i][ch][1];
            size_t wi = ((size_t)(l * DV + i) * DV + o) * (MM * MM) + xm * MM + ky;
            float wr = Wr[wi], wim = Wi[wi];
            orr += gr * wr - gi * wim;
            oii += gr * wim + gi * wr;
        }
        size_t off = (((size_t)bk * MK + m) * DV + o) * 2;   // [ky][m][co]
        F[off] = orr * scale; F[off + 1] = oii * scale;
    }
}

// -------------------- inverse iy-DFT: F -> g[b][iy][ky][co][2]  (unchanged)
__global__ __launch_bounds__(384) void k_inv1(const float* __restrict__ F,
        float* __restrict__ g)
{
    __shared__ float itw[MK * 2];
    int tid = threadIdx.x;
    int b = blockIdx.x >> 8, iy = blockIdx.x & 255;
    if (tid < MK) {
        int f = (tid < MM) ? tid : (232 + tid);
        float ang = TWO_PI_N * (float)((f * iy) & 255);
        float s, c; sincosf(ang, &s, &c);
        itw[2 * tid] = c; itw[2 * tid + 1] = s;
    }
    __syncthreads();

    int ky = tid >> 5, co = tid & 31;
    const float* Fp = F + ((size_t)(b * MM + ky) * MK) * (DV * 2) + 2 * co;
    float gr = 0.f, gi = 0.f;
    #pragma unroll
    for (int m = 0; m < MK; ++m) {
        float2 fv = *(const float2*)(Fp + (size_t)m * (DV * 2));  // coalesced
        float ic = itw[2 * m], is = itw[2 * m + 1];
        gr += fv.x * ic - fv.y * is;
        gi += fv.x * is + fv.y * ic;
    }
    size_t o = (((size_t)(b * SS + iy)) * MM + ky) * (DV * 2) + 2 * co;
    g[o] = gr; g[o + 1] = gi;
}

// ----------------- pointwise: h = relu(conv1x1(h) + invDFT(F)), in place.
// grid = NB*128; block = 2 rows x 2 j-halves, one wave per (row, j-half),
// 2 px/thread (float2). (256,4) — R14-proven form (70 us): scalar float2 math.
// R15's packed v2f version REGRESSED this kernel (90 us, VALU time unchanged,
// worse latency hiding) — keep scalar. Never raise min-waves (R13 spills).
template<int FINAL>
__global__ __launch_bounds__(256, 4) void k_pt(float* __restrict__ h,
        const float* __restrict__ g, const float* __restrict__ wT,
        const float* __restrict__ ws_b, const float* __restrict__ tw2,
        const float* __restrict__ q_w, const float* __restrict__ q_b,
        float* __restrict__ out, int l)
{
    int tid = threadIdx.x;
    int lane = tid & 63;
    int w = __builtin_amdgcn_readfirstlane(tid >> 6);
    int b  = blockIdx.x >> 7;
    int iy = ((blockIdx.x & 127) << 1) + (w >> 1);
    int j0 = ((w & 1) << 7) + (lane << 1);

    float* hb = h + ((size_t)b * DV * SS + iy) * SS + j0;
    const float* wt  = wT + (size_t)l * DV * DV;     // [ci][co], uniform
    const float* wsb = ws_b + (size_t)l * DV;

    float2 acc[DV];
    #pragma unroll
    for (int co = 0; co < DV; ++co) {
        float bv = wsb[co];
        acc[co].x = bv; acc[co].y = bv;
    }

    #pragma unroll 4
    for (int ci = 0; ci < DV; ++ci) {
        float2 hv = *(const float2*)(hb + (size_t)ci * SS * SS);
        const float* wc = wt + ci * DV;              // 32 contiguous s_loads
        #pragma unroll
        for (int co = 0; co < DV; ++co) {
            float wv = wc[co];
            acc[co].x += wv * hv.x; acc[co].y += wv * hv.y;
        }
    }

    const float* gp = g + ((size_t)(b * SS + iy)) * (MM * DV * 2);  // uniform
    #pragma unroll 2
    for (int ky = 0; ky < MM; ++ky) {
        float4 t4 = *(const float4*)(tw2 + ((size_t)ky * SS + j0) * 2);
        const float* Gk = gp + ky * (DV * 2);        // 64 contiguous s_loads
        #pragma unroll
        for (int co = 0; co < DV; ++co) {
            float gr = Gk[2 * co], gi = Gk[2 * co + 1];
            acc[co].x += gr * t4.x - gi * t4.y;
            acc[co].y += gr * t4.z - gi * t4.w;
        }
    }

    if (FINAL) {
        float qb = q_b[0];
        float2 o2; o2.x = qb; o2.y = qb;
        #pragma unroll
        for (int co = 0; co < DV; ++co) {
            float qv = q_w[co];
            o2.x += qv * acc[co].x; o2.y += qv * acc[co].y;
        }
        *(float2*)(out + ((size_t)(b * SS + iy)) * SS + j0) = o2;
    } else {
        #pragma unroll
        for (int co = 0; co < DV; ++co) {
            float2 v;
            v.x = fmaxf(acc[co].x, 0.f); v.y = fmaxf(acc[co].y, 0.f);
            *(float2*)(hb + (size_t)co * SS * SS) = v;
        }
    }
}

extern "C" void kernel_launch(void* const* d_in, const int* in_sizes, int n_in,
                              void* d_out, int out_size, void* d_ws, size_t ws_size,
                              hipStream_t stream)
{
    const float* x    = (const float*)d_in[0];
    const float* p_w  = (const float*)d_in[1];
    const float* p_b  = (const float*)d_in[2];
    const float* ws_w = (const float*)d_in[3];
    const float* ws_b = (const float*)d_in[4];
    const float* w1r  = (const float*)d_in[5];
    const float* w1i  = (const float*)d_in[6];
    const float* w2r  = (const float*)d_in[7];
    const float* w2i  = (const float*)d_in[8];
    const float* q_w  = (const float*)d_in[9];
    const float* q_b  = (const float*)d_in[10];
    float* out = (float*)d_out;

    float* h   = (float*)d_ws;
    float* A   = h   + (size_t)NB * DV * SS * SS;
    float* F   = A   + (size_t)NB * MM * DV * SS * 2;
    float* g   = F   + (size_t)NB * MM * MK * DV * 2;
    float* twT = g   + (size_t)NB * SS * MM * DV * 2;
    float* wT  = twT + (size_t)SS * MM * 2;
    float* tw2 = wT  + (size_t)LL * DV * DV;

    dim3 blk(256);
    k_prep<<<1, blk, 0, stream>>>(ws_w, twT, wT, tw2);
    k_lift<<<NB * 64, blk, 0, stream>>>(x, p_w, p_b, h);
    for (int l = 0; l < LL; ++l) {
        k_rowdft<<<NB * DV * 2, dim3(512), 0, stream>>>(h, twT, A);
        k_cm<<<NB * MM * 4, blk, 0, stream>>>(A, w1r, w1i, w2r, w2i, F, l);
        k_inv1<<<NB * SS, dim3(384), 0, stream>>>(F, g);
        if (l < LL - 1)
            k_pt<0><<<NB * 128, blk, 0, stream>>>(h, g, wT, ws_b, tw2,
                                                  nullptr, nullptr, nullptr, l);
        else
            k_pt<1><<<NB * 128, blk, 0, stream>>>(h, g, wT, ws_b, tw2,
                                                  q_w, q_b, out, l);
    }
}